// Round 13
// baseline (174.354 us; speedup 1.0000x reference)
//
#include <hip/hip_runtime.h>
#include <math.h>

typedef __attribute__((ext_vector_type(8))) short    short8;
typedef __attribute__((ext_vector_type(4))) float    f32x4;
typedef __attribute__((ext_vector_type(2))) float    f32x2;
typedef __attribute__((ext_vector_type(4))) unsigned uint4v;

#define FRAG0 256   // u32 offset of frag region in ws
#define L2E  1.44269504f      // log2(e)
#define L2E2 2.88539008f      // 2*log2(e)
#define LN2  0.69314718f

__device__ __forceinline__ unsigned short f2bf(float f) {   // RNE
    unsigned u = __builtin_bit_cast(unsigned, f);
    u = u + 0x7fffu + ((u >> 16) & 1u);
    return (unsigned short)(u >> 16);
}
__device__ __forceinline__ unsigned packRNE(float hi, float lo) {
    return (unsigned)f2bf(lo) | ((unsigned)f2bf(hi) << 16);
}
// hot-path bf16 pair pack: single VOP3 v_cvt_pk_bf16_f32 (RNE), lo -> [15:0], hi -> [31:16]
__device__ __forceinline__ unsigned cvtpk(float hi, float lo) {
    unsigned r;
    asm("v_cvt_pk_bf16_f32 %0, %1, %2" : "=v"(r) : "v"(lo), "v"(hi));
    return r;
}
__device__ __forceinline__ unsigned pack_trunc(float hi, float lo) {  // 1 v_perm
    return __builtin_amdgcn_perm(__builtin_bit_cast(unsigned, hi),
                                 __builtin_bit_cast(unsigned, lo), 0x07060302u);
}
__device__ __forceinline__ float rfl(float x) {
    return __builtin_bit_cast(float, __builtin_amdgcn_readfirstlane(__builtin_bit_cast(int, x)));
}
__device__ __forceinline__ f32x4 mfma16(short8 a, short8 b, f32x4 c) {
    return __builtin_amdgcn_mfma_f32_16x16x32_bf16(a, b, c, 0, 0, 0);
}
__device__ __forceinline__ unsigned bperm(int addr, unsigned v) {
    return (unsigned)__builtin_amdgcn_ds_bpermute(addr, (int)v);
}
// DPP helpers: quad_perm xor1 = 0xB1, xor2 = 0x4E; row_shl:N = 0x100+N (lane i <- lane i+N)
template<int CTRL>
__device__ __forceinline__ unsigned dppu(unsigned v) {
    return (unsigned)__builtin_amdgcn_update_dpp((int)v, (int)v, CTRL, 0xF, 0xF, false);
}
template<int CTRL>
__device__ __forceinline__ float dppf(float v) {
    int i = __builtin_bit_cast(int, v);
    return __builtin_bit_cast(float, __builtin_amdgcn_update_dpp(i, i, CTRL, 0xF, 0xF, false));
}
#define DPP_XOR1 0xB1
#define DPP_XOR2 0x4E
#define DPP_SHL1 0x101
#define DPP_SHL4 0x104
#define DPP_SHL5 0x105

// raw transcendental builtins: single v_exp_f32 / v_log_f32 (no OCML edge-handling)
__device__ __forceinline__ float ex2(float x) { return __builtin_amdgcn_exp2f(x); }
__device__ __forceinline__ float lg2(float x) { return __builtin_amdgcn_logf(x); }
// gates with log2e pre-folded into weights: no scale muls on the chain
__device__ __forceinline__ float sig2(float xs)  { return __builtin_amdgcn_rcpf(1.f + ex2(-xs)); }
__device__ __forceinline__ float tanh2(float ys) { return 1.f - 2.f * __builtin_amdgcn_rcpf(ex2(ys) + 1.f); }
__device__ __forceinline__ f32x4 ld4(const float* p) { return *(const f32x4*)p; }

// packed-f32 VOP3P (gfx90a+): one instr = 2 elementwise f32 ops
__device__ __forceinline__ f32x2 pkadd(f32x2 a, f32x2 b) {
    f32x2 r; asm("v_pk_add_f32 %0, %1, %2" : "=v"(r) : "v"(a), "v"(b)); return r;
}
__device__ __forceinline__ f32x2 pkmul(f32x2 a, f32x2 b) {
    f32x2 r; asm("v_pk_mul_f32 %0, %1, %2" : "=v"(r) : "v"(a), "v"(b)); return r;
}
__device__ __forceinline__ f32x2 pkfma(f32x2 a, f32x2 b, f32x2 c) {
    f32x2 r; asm("v_pk_fma_f32 %0, %1, %2, %3" : "=v"(r) : "v"(a), "v"(b), "v"(c)); return r;
}
#define LO2(v) __builtin_shufflevector(v, v, 0, 1)
#define HI2(v) __builtin_shufflevector(v, v, 2, 3)

__device__ __forceinline__ void packC(unsigned* P, f32x4 a0, f32x4 a1, bool oob) {
    float r0 = fmaxf(a0[0], 0.f), r1 = fmaxf(a0[1], 0.f), r2 = fmaxf(a0[2], 0.f), r3 = fmaxf(a0[3], 0.f);
    float s0 = fmaxf(a1[0], 0.f), s1 = fmaxf(a1[1], 0.f), s2 = fmaxf(a1[2], 0.f), s3 = fmaxf(a1[3], 0.f);
    P[0] = pack_trunc(r1, r0); P[1] = pack_trunc(r3, r2);
    P[2] = pack_trunc(s1, s0); P[3] = pack_trunc(s3, s2);
    if (oob) { P[0] = 0u; P[1] = 0u; P[2] = 0u; P[3] = 0u; }
}

// ===================== prep kernel: MLP compose + frag prepack =====================
__global__ __launch_bounds__(256) void r2p2_prep(
    const float* __restrict__ w0, const float* __restrict__ w1,
    const float* __restrict__ w2, const float* __restrict__ w3,
    const float* __restrict__ enc_whh,
    const float* __restrict__ dec_wih, const float* __restrict__ dec_whh,
    const float* __restrict__ mw1, const float* __restrict__ mb1,
    const float* __restrict__ mw2, const float* __restrict__ mb2,
    float* __restrict__ wsf, unsigned* __restrict__ wsu) {
    const int tid = threadIdx.x, bx = blockIdx.x;
    if (bx == 0) {
        // ---- composed MLP, coalesced: threads 0..127 -> M[j][k]; 128..191 -> c partials ----
        __shared__ float red[64];
        if (tid < 128) {
            int k = tid & 31, j = tid >> 5;
            const float* w2r = mw2 + j * 512;
            float a0 = 0.f, a1 = 0.f, a2 = 0.f, a3 = 0.f;
#pragma unroll 4
            for (int m = 0; m < 512; m += 4) {
                a0 = fmaf(w2r[m],     mw1[m * 32 + k],       a0);
                a1 = fmaf(w2r[m + 1], mw1[(m + 1) * 32 + k], a1);
                a2 = fmaf(w2r[m + 2], mw1[(m + 2) * 32 + k], a2);
                a3 = fmaf(w2r[m + 3], mw1[(m + 3) * 32 + k], a3);
            }
            wsf[j * 32 + k] = (a0 + a1) + (a2 + a3);
        } else if (tid < 192) {
            int t = tid - 128;          // 0..63: j = t&3, chunk = t>>2 (16 chunks of 32)
            int j = t & 3, ch = t >> 2;
            const float* w2c = mw2 + j * 512 + ch * 32;
            const float* b1c = mb1 + ch * 32;
            float p = 0.f;
#pragma unroll 8
            for (int m = 0; m < 32; ++m) p = fmaf(w2c[m], b1c[m], p);
            red[t] = p;
        }
        __syncthreads();
        if (tid < 4) {
            float c = mb2[tid];
#pragma unroll
            for (int i = 0; i < 16; ++i) c += red[tid + i * 4];
            wsf[128 + tid] = c;
        }
        return;
    }
    // ---- frag prepack: 44 frags x 64 lanes, cells split over blocks 1..7 ----
    // GRU frags (f>=26) pre-scaled: R/Z gates by log2e, N gate by 2*log2e (folds the
    // exp/tanh argument scaling out of the recurrent hot path).
    int base = (bx - 1) * 416;
    for (int c = base + tid; c < base + 416 && c < 2816; c += 256) {
        int f = c >> 6, lane = c & 63;
        int n = lane & 15, q = lane >> 4;
        int pc0 = ((n >> 2) << 3) | (n & 3);
        float v[8];
        float sc = 1.f;
        if (f < 2) {
            int co = pc0 + f * 4;
#pragma unroll
            for (int j = 0; j < 8; ++j) v[j] = (q == 0) ? w0[j * 32 + co] : 0.f;
        } else if (f < 26) {
            int t = f - 2;
            const float* W = (t < 8) ? w1 : (t < 16) ? w2 : w3;
            t &= 7;
            int mt = t >> 2, ks = t & 3, co = pc0 + mt * 4;
#pragma unroll
            for (int j = 0; j < 8; ++j) v[j] = W[(ks * 32 + q * 8 + j) * 32 + co];
        } else if (f < 32) {
            int t = f - 26, gate = t >> 1, mt = t & 1;
            sc = (gate == 2) ? L2E2 : L2E;
            int row = gate * 32 + pc0 + mt * 4;
#pragma unroll
            for (int j = 0; j < 8; ++j) v[j] = dec_wih[row * 34 + 2 + q * 8 + j];
        } else if (f < 38) {
            int t = f - 32, gate = t >> 1, mt = t & 1;
            sc = (gate == 2) ? L2E2 : L2E;
            int row = gate * 32 + pc0 + mt * 4;
#pragma unroll
            for (int j = 0; j < 8; ++j) v[j] = dec_whh[row * 32 + q * 8 + j];
        } else {
            int t = f - 38, gate = t >> 1, mt = t & 1;
            sc = (gate == 2) ? L2E2 : L2E;
            int row = gate * 32 + pc0 + mt * 4;
#pragma unroll
            for (int j = 0; j < 8; ++j) v[j] = enc_whh[row * 32 + q * 8 + j];
        }
#pragma unroll
        for (int j = 0; j < 8; ++j) v[j] *= sc;
        uint4v u;
        u[0] = packRNE(v[1], v[0]); u[1] = packRNE(v[3], v[2]);
        u[2] = packRNE(v[5], v[4]); u[3] = packRNE(v[7], v[6]);
        *(uint4v*)(wsu + FRAG0 + f * 256 + lane * 4) = u;
    }
}

// ===================== main kernel =====================
__global__ __launch_bounds__(256)
void r2p2_main(
    const float* __restrict__ z, const float* __restrict__ past, const float* __restrict__ lidar,
    const float* __restrict__ b0, const float* __restrict__ b1,
    const float* __restrict__ b2, const float* __restrict__ b3,
    const float* __restrict__ enc_wih, const float* __restrict__ enc_bih, const float* __restrict__ enc_bhh,
    const float* __restrict__ dec_wih, const float* __restrict__ dec_bih, const float* __restrict__ dec_bhh,
    const float* __restrict__ wsf, const unsigned* __restrict__ wsu,
    float* __restrict__ out) {

    const int tid = threadIdx.x, b = blockIdx.x;
    const int wid = tid >> 6, lane = tid & 63;
    const int n = lane & 15, q = lane >> 4, e = n & 1;

    __shared__ __align__(16) unsigned sLID[104 * 104];
    __shared__ __align__(16) float PASTs[40];
    __shared__ __align__(16) float ZVs[64];

    if (wid != 0) {
        // ====== waves 1-3: lidar staging + z (z pre-scaled by ln2 for softplus folding) ======
        int st = tid - 64;   // 0..191
        if (st < 60) ZVs[st] = z[b * 60 + st] * LN2;
        for (int i = st; i < 816; i += 192) {   // zero border
            int idx = (i < 416) ? (10400 + i) : ((((i - 416) >> 2) * 104) + 100 + ((i - 416) & 3));
            sLID[idx] = 0u;
        }
        const float4* lp4 = (const float4*)(lidar + (size_t)b * 20000);
#pragma unroll 4
        for (int i = st; i < 5000; i += 192) {
            int r = (int)(((unsigned)i * 5243u) >> 18);   // i / 50
            int c2 = i - r * 50;
            float4 v = lp4[i];
            int o = r * 104 + 2 * c2;
            sLID[o]     = pack_trunc(v.y, v.x);
            sLID[o + 1] = pack_trunc(v.w, v.z);
        }
        __syncthreads();
        return;
    }

    // ====== wave 0: coalesced frag loads ======
    uint4v FR[44];
#pragma unroll
    for (int f = 0; f < 44; ++f) FR[f] = *(const uint4v*)(wsu + FRAG0 + f * 256 + lane * 4);
#define FRG(f) __builtin_bit_cast(short8, FR[f])

    f32x4 cb0[2], cb1[2], cb2[2], cb3[2], gbR[2], gbZ[2], gbNi[2], gbNh[2];
    f32x4 egR[2], egZ[2], egNh[2];
#pragma unroll
    for (int mt = 0; mt < 2; ++mt) {
        int o = q * 8 + mt * 4;
        cb0[mt] = ld4(b0 + o); cb1[mt] = ld4(b1 + o); cb2[mt] = ld4(b2 + o); cb3[mt] = ld4(b3 + o);
        gbR[mt]  = (ld4(dec_bih + o)      + ld4(dec_bhh + o))      * L2E;
        gbZ[mt]  = (ld4(dec_bih + 32 + o) + ld4(dec_bhh + 32 + o)) * L2E;
        gbNi[mt] = ld4(dec_bih + 64 + o) * L2E2;
        gbNh[mt] = ld4(dec_bhh + 64 + o) * L2E2;
        egR[mt]  = (ld4(enc_bih + o)      + ld4(enc_bhh + o))      * L2E;
        egZ[mt]  = (ld4(enc_bih + 32 + o) + ld4(enc_bhh + 32 + o)) * L2E;
        egNh[mt] = ld4(enc_bhh + 64 + o) * L2E2;
    }
    f32x4 ebni = ld4(enc_bih + 64 + q * 8 + e * 4) * L2E2;
    // gate x-weights, packed across r-pairs: [i] = {w[2i], w[2i+1]}
    f32x2 wxrx[2], wxry[2], wxzx[2], wxzy[2], wxnx[2], wxny[2];
    f32x2 wexrx[2], wexry[2], wexzx[2], wexzy[2], wexnx[2], wexny[2];
#pragma unroll
    for (int i = 0; i < 2; ++i) {
        float2 a, bb;
        int c0i = q * 8 + e * 4 + 2 * i, c1i = c0i + 1;
        a = *(const float2*)(dec_wih + c0i * 34); bb = *(const float2*)(dec_wih + c1i * 34);
        wxrx[i] = f32x2{a.x, bb.x} * L2E;  wxry[i] = f32x2{a.y, bb.y} * L2E;
        a = *(const float2*)(dec_wih + (32 + c0i) * 34); bb = *(const float2*)(dec_wih + (32 + c1i) * 34);
        wxzx[i] = f32x2{a.x, bb.x} * L2E;  wxzy[i] = f32x2{a.y, bb.y} * L2E;
        a = *(const float2*)(dec_wih + (64 + c0i) * 34); bb = *(const float2*)(dec_wih + (64 + c1i) * 34);
        wxnx[i] = f32x2{a.x, bb.x} * L2E2; wxny[i] = f32x2{a.y, bb.y} * L2E2;
        a = *(const float2*)(enc_wih + c0i * 2); bb = *(const float2*)(enc_wih + c1i * 2);
        wexrx[i] = f32x2{a.x, bb.x} * L2E;  wexry[i] = f32x2{a.y, bb.y} * L2E;
        a = *(const float2*)(enc_wih + (32 + c0i) * 2); bb = *(const float2*)(enc_wih + (32 + c1i) * 2);
        wexzx[i] = f32x2{a.x, bb.x} * L2E;  wexzy[i] = f32x2{a.y, bb.y} * L2E;
        a = *(const float2*)(enc_wih + (64 + c0i) * 2); bb = *(const float2*)(enc_wih + (64 + c1i) * 2);
        wexnx[i] = f32x2{a.x, bb.x} * L2E2; wexny[i] = f32x2{a.y, bb.y} * L2E2;
    }
    // head rows 2,3 (scale outputs) pre-scaled by log2e -> softplus in base-2
    short8 Am = (short8)0;
    if (n < 4) {
        float sc = (n >= 2) ? L2E : 1.f;
#pragma unroll
        for (int j = 0; j < 8; ++j) Am[j] = (short)f2bf(wsf[n * 32 + q * 8 + j] * sc);
    }
    f32x4 mcv = {0.f, 0.f, 0.f, 0.f};
    if (q == 0) {
        mcv = *(const f32x4*)(wsf + 128);
        mcv[2] *= L2E; mcv[3] *= L2E;
    }

    if (lane < 20) *(float2*)&PASTs[2 * lane] = *(const float2*)(past + b * 40 + 2 * lane);
    float q0 = past[b * 40 + 38], q1 = past[b * 40 + 39];
    float p0 = past[b * 40 + 36], p1 = past[b * 40 + 37];
    asm volatile("s_waitcnt lgkmcnt(0)" ::: "memory");

    // ====== encoder: register GRU, 20 steps ======
    float hq[4] = {0.f, 0.f, 0.f, 0.f};
    short8 hfr = (short8)0;
#pragma unroll 1
    for (int t = 0; t < 20; ++t) {
        float2 xp = *(const float2*)&PASTs[2 * t];
        f32x4 gr0 = mfma16(FRG(38), hfr, egR[0]),  gr1 = mfma16(FRG(39), hfr, egR[1]);
        f32x4 gz0 = mfma16(FRG(40), hfr, egZ[0]),  gz1 = mfma16(FRG(41), hfr, egZ[1]);
        f32x4 gh0 = mfma16(FRG(42), hfr, egNh[0]), gh1 = mfma16(FRG(43), hfr, egNh[1]);
        f32x2 x0 = {xp.x, xp.x}, x1 = {xp.y, xp.y};
        f32x2 xrp[2], xzp[2], xnp[2];
#pragma unroll
        for (int i = 0; i < 2; ++i) {
            xrp[i] = pkfma(x1, wexry[i], pkmul(x0, wexrx[i]));
            xzp[i] = pkfma(x1, wexzy[i], pkmul(x0, wexzx[i]));
            xnp[i] = pkfma(x1, wexny[i], pkmul(x0, wexnx[i]));
        }
        f32x4 grS = e ? gr1 : gr0, gzS = e ? gz1 : gz0, ghS = e ? gh1 : gh0;
        f32x2 sr0 = pkadd(LO2(grS), xrp[0]), sr1 = pkadd(HI2(grS), xrp[1]);
        f32x2 sz0 = pkadd(LO2(gzS), xzp[0]), sz1 = pkadd(HI2(gzS), xzp[1]);
        f32x2 sn0 = pkadd(LO2(ebni), xnp[0]), sn1 = pkadd(HI2(ebni), xnp[1]);
        float srA[4] = {sr0[0], sr0[1], sr1[0], sr1[1]};
        float szA[4] = {sz0[0], sz0[1], sz1[0], sz1[1]};
        float snA[4] = {sn0[0], sn0[1], sn1[0], sn1[1]};
        float hn[4];
#pragma unroll
        for (int r = 0; r < 4; ++r) {
            float rr = sig2(srA[r]), zz = sig2(szA[r]);
            float tn = tanh2(fmaf(rr, ghS[r], snA[r]));
            float hv = tn + zz * (hq[r] - tn);
            hq[r] = hv; hn[r] = hv;
        }
        unsigned hu0 = cvtpk(hn[1], hn[0]), hu1 = cvtpk(hn[3], hn[2]);
        unsigned po0 = dppu<DPP_XOR1>(hu0), po1 = dppu<DPP_XOR1>(hu1);
        uint4v hv4;
        hv4[0] = e ? po0 : hu0; hv4[1] = e ? po1 : hu1;
        hv4[2] = e ? hu0 : po0; hv4[3] = e ? hu1 : po1;
        hfr = __builtin_bit_cast(short8, hv4);
    }

    // early-issue h-dependent decoder GRU MFMAs for step 0 (overlap sync wait)
    f32x4 hr0 = mfma16(FRG(32), hfr, gbR[0]);
    f32x4 hr1 = mfma16(FRG(33), hfr, gbR[1]);
    f32x4 hz0 = mfma16(FRG(34), hfr, gbZ[0]);
    f32x4 hz1 = mfma16(FRG(35), hfr, gbZ[1]);
    f32x4 hgn0 = mfma16(FRG(36), hfr, gbNh[0]);
    f32x4 hgn1 = mfma16(FRG(37), hfr, gbNh[1]);

    __syncthreads();   // join staging waves

    // ---- loop-invariant layout constants ----
    const int py1 = n >> 2, px1 = n & 3;       // conv1/conv2 column -> position (4-wide linear)
    const int woff = py1 * 104 + px1;          // per-lane sLID window base offset
    // conv3 gather (bpermute, replicated every quad) from conv2's 4-wide layout
    const int py3 = (n >> 1) & 1, px3 = n & 1;
    int adr3[4];
#pragma unroll
    for (int ks = 0; ks < 4; ++ks)
        adr3[ks] = (q * 16 + (py3 + (ks >> 1)) * 4 + px3 + (ks & 1)) * 4;
    const f32x4 zf4 = {0.f, 0.f, 0.f, 0.f};
    float la = 0.f;   // base-2 accumulator; converted at final store

    // ---- software-pipelined window state ----
    float ay, ax; int limy, limx;
    unsigned W9[9];
    {
        float f0 = fminf(fmaxf(floorf(q0), 0.f), 98.f);
        float f1v = fminf(fmaxf(floorf(q1), 0.f), 98.f);
        int fy = (int)f0, fx = (int)f1v;
        ay = fminf(fmaxf(q0 - f0, 0.f), 1.f);
        ax = fminf(fmaxf(q1 - f1v, 0.f), 1.f);
        limy = 100 - fy; limx = 100 - fx;
        int bw = fy * 104 + fx + woff;
#pragma unroll
        for (int ry = 0; ry < 3; ++ry)
#pragma unroll
            for (int rx = 0; rx < 3; ++rx)
                W9[ry * 3 + rx] = sLID[bw + ry * 104 + rx];
    }

#pragma unroll 1
    for (int t = 0; t < 30; ++t) {
        float2 zv = *(const float2*)&ZVs[2 * t];

        // ---- fused conv0: 4 tap-aligned layouts, no conv1 gather (W9 preloaded) ----
        short8 bf1[4];
#pragma unroll
        for (int ks = 0; ks < 4; ++ks) {
            int dy = ks >> 1, dx = ks & 1;
            int wb = dy * 3 + dx;
            uint4v u;
            u[0] = W9[wb];     u[1] = W9[wb + 1];
            u[2] = W9[wb + 3]; u[3] = W9[wb + 4];
            short8 bq = __builtin_bit_cast(short8, u);
            f32x4 c0 = mfma16(FRG(0), bq, cb0[0]);
            f32x4 c1 = mfma16(FRG(1), bq, cb0[1]);
            unsigned P[4];
            packC(P, c0, c1, (py1 + dy >= limy) || (px1 + dx >= limx));
            uint4v up; up[0] = P[0]; up[1] = P[1]; up[2] = P[2]; up[3] = P[3];
            bf1[ks] = __builtin_bit_cast(short8, up);
        }

        // ---- conv1 (pk_add merges) ----
        unsigned Pa[4];
        {
            f32x4 aA = mfma16(FRG(2), bf1[0], cb1[0]); aA = mfma16(FRG(3), bf1[1], aA);
            f32x4 aB = mfma16(FRG(4), bf1[2], zf4);    aB = mfma16(FRG(5), bf1[3], aB);
            f32x4 bA = mfma16(FRG(6), bf1[0], cb1[1]); bA = mfma16(FRG(7), bf1[1], bA);
            f32x4 bB = mfma16(FRG(8), bf1[2], zf4);    bB = mfma16(FRG(9), bf1[3], bB);
            f32x2 o0l = pkadd(LO2(aA), LO2(aB)), o0h = pkadd(HI2(aA), HI2(aB));
            f32x2 o1l = pkadd(LO2(bA), LO2(bB)), o1h = pkadd(HI2(bA), HI2(bB));
            f32x4 o0 = __builtin_shufflevector(o0l, o0h, 0, 1, 2, 3);
            f32x4 o1 = __builtin_shufflevector(o1l, o1h, 0, 1, 2, 3);
            packC(Pa, o0, o1, (py1 >= limy) || (px1 >= limx));
        }

        // ---- conv2 : DPP row_shl gather (sources lanes n+{0,1,4,5}) ----
        short8 bf2v[4];
        {
            uint4v g0, g1, g2, g3;
#pragma unroll
            for (int u = 0; u < 4; ++u) {
                g0[u] = Pa[u];
                g1[u] = dppu<DPP_SHL1>(Pa[u]);
                g2[u] = dppu<DPP_SHL4>(Pa[u]);
                g3[u] = dppu<DPP_SHL5>(Pa[u]);
            }
            bf2v[0] = __builtin_bit_cast(short8, g0);
            bf2v[1] = __builtin_bit_cast(short8, g1);
            bf2v[2] = __builtin_bit_cast(short8, g2);
            bf2v[3] = __builtin_bit_cast(short8, g3);
        }
        unsigned Pb[4];
        {
            f32x4 aA = mfma16(FRG(10), bf2v[0], cb2[0]); aA = mfma16(FRG(11), bf2v[1], aA);
            f32x4 aB = mfma16(FRG(12), bf2v[2], zf4);    aB = mfma16(FRG(13), bf2v[3], aB);
            f32x4 bA = mfma16(FRG(14), bf2v[0], cb2[1]); bA = mfma16(FRG(15), bf2v[1], bA);
            f32x4 bB = mfma16(FRG(16), bf2v[2], zf4);    bB = mfma16(FRG(17), bf2v[3], bB);
            f32x2 o0l = pkadd(LO2(aA), LO2(aB)), o0h = pkadd(HI2(aA), HI2(aB));
            f32x2 o1l = pkadd(LO2(bA), LO2(bB)), o1h = pkadd(HI2(bA), HI2(bB));
            f32x4 o0 = __builtin_shufflevector(o0l, o0h, 0, 1, 2, 3);
            f32x4 o1 = __builtin_shufflevector(o1l, o1h, 0, 1, 2, 3);
            packC(Pb, o0, o1, (py1 >= limy) || (px1 >= limx));
        }

        // ---- conv3 (bpermute, quad-replicated) + bilinear (pk_mul + DPP quad butterfly) ----
        short8 bf3v[4];
#pragma unroll
        for (int ks = 0; ks < 4; ++ks) {
            uint4v bu;
#pragma unroll
            for (int u = 0; u < 4; ++u) bu[u] = bperm(adr3[ks], Pb[u]);
            bf3v[ks] = __builtin_bit_cast(short8, bu);
        }
        short8 xf;
        {
            f32x4 aA = mfma16(FRG(18), bf3v[0], cb3[0]); aA = mfma16(FRG(19), bf3v[1], aA);
            f32x4 aB = mfma16(FRG(20), bf3v[2], zf4);    aB = mfma16(FRG(21), bf3v[3], aB);
            f32x4 bA = mfma16(FRG(22), bf3v[0], cb3[1]); bA = mfma16(FRG(23), bf3v[1], bA);
            f32x4 bB = mfma16(FRG(24), bf3v[2], zf4);    bB = mfma16(FRG(25), bf3v[3], bB);
            f32x2 o0l = pkadd(LO2(aA), LO2(aB)), o0h = pkadd(HI2(aA), HI2(aB));
            f32x2 o1l = pkadd(LO2(bA), LO2(bB)), o1h = pkadd(HI2(bA), HI2(bB));
            float wy = (n & 2) ? ay : 1.f - ay;
            float wx = (n & 1) ? ax : 1.f - ax;
            float w = wy * wx;                    // w >= 0, so relu(x)*w == relu(x*w)
            f32x2 w2 = {w, w};
            f32x2 m0l = pkmul(o0l, w2), m0h = pkmul(o0h, w2);
            f32x2 m1l = pkmul(o1l, w2), m1h = pkmul(o1h, w2);
            float t0[4] = {fmaxf(m0l[0], 0.f), fmaxf(m0l[1], 0.f), fmaxf(m0h[0], 0.f), fmaxf(m0h[1], 0.f)};
            float t1[4] = {fmaxf(m1l[0], 0.f), fmaxf(m1l[1], 0.f), fmaxf(m1h[0], 0.f), fmaxf(m1h[1], 0.f)};
#pragma unroll
            for (int r = 0; r < 4; ++r) {
                t0[r] += dppf<DPP_XOR1>(t0[r]); t1[r] += dppf<DPP_XOR1>(t1[r]);
                t0[r] += dppf<DPP_XOR2>(t0[r]); t1[r] += dppf<DPP_XOR2>(t1[r]);
            }
            uint4v xu;
            xu[0] = cvtpk(t0[1], t0[0]); xu[1] = cvtpk(t0[3], t0[2]);
            xu[2] = cvtpk(t1[1], t1[0]); xu[3] = cvtpk(t1[3], t1[2]);
            xf = __builtin_bit_cast(short8, xu);
        }

        // ---- decoder GRU (h-dependent halves precomputed last step) ----
        f32x4 gr0 = mfma16(FRG(26), xf, hr0);
        f32x4 gr1 = mfma16(FRG(27), xf, hr1);
        f32x4 gz0 = mfma16(FRG(28), xf, hz0);
        f32x4 gz1 = mfma16(FRG(29), xf, hz1);
        f32x4 gi0 = mfma16(FRG(30), xf, gbNi[0]);
        f32x4 gi1 = mfma16(FRG(31), xf, gbNi[1]);
        // gate x-parts (packed), under the MFMA latency above
        f32x2 q02 = {q0, q0}, q12 = {q1, q1};
        f32x2 xrp[2], xzp[2], xnp[2];
#pragma unroll
        for (int i = 0; i < 2; ++i) {
            xrp[i] = pkfma(q12, wxry[i], pkmul(q02, wxrx[i]));
            xzp[i] = pkfma(q12, wxzy[i], pkmul(q02, wxzx[i]));
            xnp[i] = pkfma(q12, wxny[i], pkmul(q02, wxnx[i]));
        }
        f32x4 grS = e ? gr1 : gr0, gzS = e ? gz1 : gz0, giS = e ? gi1 : gi0, ghS = e ? hgn1 : hgn0;
        f32x2 sr0 = pkadd(LO2(grS), xrp[0]), sr1 = pkadd(HI2(grS), xrp[1]);
        f32x2 sz0 = pkadd(LO2(gzS), xzp[0]), sz1 = pkadd(HI2(gzS), xzp[1]);
        f32x2 sn0 = pkadd(LO2(giS), xnp[0]), sn1 = pkadd(HI2(giS), xnp[1]);
        float srA[4] = {sr0[0], sr0[1], sr1[0], sr1[1]};
        float szA[4] = {sz0[0], sz0[1], sz1[0], sz1[1]};
        float snA[4] = {sn0[0], sn0[1], sn1[0], sn1[1]};
        float hn[4];
#pragma unroll
        for (int r = 0; r < 4; ++r) {
            float rr = sig2(srA[r]), zz = sig2(szA[r]);
            float tn = tanh2(fmaf(rr, ghS[r], snA[r]));
            float hv = tn + zz * (hq[r] - tn);
            hq[r] = hv; hn[r] = hv;
        }
        unsigned hu0 = cvtpk(hn[1], hn[0]), hu1 = cvtpk(hn[3], hn[2]);
        unsigned po0 = dppu<DPP_XOR1>(hu0), po1 = dppu<DPP_XOR1>(hu1);
        uint4v hv4;
        hv4[0] = e ? po0 : hu0; hv4[1] = e ? po1 : hu1;
        hv4[2] = e ? hu0 : po0; hv4[3] = e ? hu1 : po1;
        hfr = __builtin_bit_cast(short8, hv4);

        // ---- head ----
        f32x4 ls = mfma16(Am, hfr, mcv);

        // early-issue next step's h-dependent GRU MFMAs (overlap head/softplus/sLID)
        hr0 = mfma16(FRG(32), hfr, gbR[0]);
        hr1 = mfma16(FRG(33), hfr, gbR[1]);
        hz0 = mfma16(FRG(34), hfr, gbZ[0]);
        hz1 = mfma16(FRG(35), hfr, gbZ[1]);
        hgn0 = mfma16(FRG(36), hfr, gbNh[0]);
        hgn1 = mfma16(FRG(37), hfr, gbNh[1]);

        // ---- tail : base-2 softplus (raw v_exp/v_log), ln2 folded into zv and final la ----
        float l2 = ls[2], l3 = ls[3];    // pre-scaled by log2e via Am/mcv
        float s0 = fmaxf(l2, 0.f) + lg2(1.f + ex2(-fabsf(l2)));
        float s1 = fmaxf(l3, 0.f) + lg2(1.f + ex2(-fabsf(l3)));
        float ny0 = 2.f * q0 - p0 + ls[0] + s0 * zv.x;
        float ny1 = 2.f * q1 - p1 + ls[1] + s1 * zv.y;
        if (lane == 0) {
            float2 o2 = {ny0, ny1};
            *(float2*)(out + b * 60 + 2 * t) = o2;
        }
        p0 = q0; p1 = q1;
        q0 = rfl(ny0); q1 = rfl(ny1);

        // ---- issue next iteration's window loads ASAP ----
        {
            float f0 = fminf(fmaxf(floorf(q0), 0.f), 98.f);
            float f1v = fminf(fmaxf(floorf(q1), 0.f), 98.f);
            int fy = (int)f0, fx = (int)f1v;
            ay = fminf(fmaxf(q0 - f0, 0.f), 1.f);
            ax = fminf(fmaxf(q1 - f1v, 0.f), 1.f);
            limy = 100 - fy; limx = 100 - fx;
            int bw = fy * 104 + fx + woff;
#pragma unroll
            for (int ry = 0; ry < 3; ++ry)
#pragma unroll
                for (int rx = 0; rx < 3; ++rx)
                    W9[ry * 3 + rx] = sLID[bw + ry * 104 + rx];
        }
        la += lg2(s0 * s1);
    }
    // la(base2) -> ln: la_e = ln2*la + 60*ln(ln2)   (s = ln2*sp per scale, 2 scales/step)
    if (lane == 0) out[15360 + b] = fmaf(LN2, la, -21.990775f);
#undef FRG
}

extern "C" void kernel_launch(void* const* d_in, const int* in_sizes, int n_in,
                              void* d_out, int out_size, void* d_ws, size_t ws_size,
                              hipStream_t stream) {
    const float* z    = (const float*)d_in[0];
    const float* past = (const float*)d_in[1];
    const float* lid  = (const float*)d_in[2];
    const float* c0w = (const float*)d_in[3];  const float* c0b = (const float*)d_in[4];
    const float* c1w = (const float*)d_in[5];  const float* c1b = (const float*)d_in[6];
    const float* c2w = (const float*)d_in[7];  const float* c2b = (const float*)d_in[8];
    const float* c3w = (const float*)d_in[9];  const float* c3b = (const float*)d_in[10];
    const float* ewih = (const float*)d_in[11]; const float* ewhh = (const float*)d_in[12];
    const float* ebih = (const float*)d_in[13]; const float* ebhh = (const float*)d_in[14];
    const float* dwih = (const float*)d_in[15]; const float* dwhh = (const float*)d_in[16];
    const float* dbih = (const float*)d_in[17]; const float* dbhh = (const float*)d_in[18];
    const float* mw1 = (const float*)d_in[19]; const float* mb1 = (const float*)d_in[20];
    const float* mw2 = (const float*)d_in[21]; const float* mb2 = (const float*)d_in[22];
    float* out = (float*)d_out;
    float* wsf = (float*)d_ws;
    unsigned* wsu = (unsigned*)d_ws;

    r2p2_prep<<<8, 256, 0, stream>>>(c0w, c1w, c2w, c3w, ewhh, dwih, dwhh,
                                     mw1, mb1, mw2, mb2, wsf, wsu);
    r2p2_main<<<256, 256, 0, stream>>>(z, past, lid, c0b, c1b, c2b, c3b,
                                       ewih, ebih, ebhh, dwih, dbih, dbhh,
                                       wsf, wsu, out);
}

// Round 16
// 169.856 us; speedup vs baseline: 1.0265x; 1.0265x over previous
//
#include <hip/hip_runtime.h>
#include <math.h>

typedef __attribute__((ext_vector_type(8))) short    short8;
typedef __attribute__((ext_vector_type(4))) float    f32x4;
typedef __attribute__((ext_vector_type(4))) unsigned uint4v;

#define FRAG0 256   // u32 offset of frag region in ws
#define L2E  1.44269504f      // log2(e)
#define L2E2 2.88539008f      // 2*log2(e)
#define LN2  0.69314718f

__device__ __forceinline__ unsigned short f2bf(float f) {   // RNE
    unsigned u = __builtin_bit_cast(unsigned, f);
    u = u + 0x7fffu + ((u >> 16) & 1u);
    return (unsigned short)(u >> 16);
}
__device__ __forceinline__ unsigned packRNE(float hi, float lo) {
    return (unsigned)f2bf(lo) | ((unsigned)f2bf(hi) << 16);
}
// hot-path bf16 pair pack: single VOP3 v_cvt_pk_bf16_f32 (RNE), lo -> [15:0], hi -> [31:16]
__device__ __forceinline__ unsigned cvtpk(float hi, float lo) {
    unsigned r;
    asm("v_cvt_pk_bf16_f32 %0, %1, %2" : "=v"(r) : "v"(lo), "v"(hi));
    return r;
}
__device__ __forceinline__ unsigned pack_trunc(float hi, float lo) {  // 1 v_perm
    return __builtin_amdgcn_perm(__builtin_bit_cast(unsigned, hi),
                                 __builtin_bit_cast(unsigned, lo), 0x07060302u);
}
__device__ __forceinline__ float rfl(float x) {
    return __builtin_bit_cast(float, __builtin_amdgcn_readfirstlane(__builtin_bit_cast(int, x)));
}
__device__ __forceinline__ f32x4 mfma16(short8 a, short8 b, f32x4 c) {
    return __builtin_amdgcn_mfma_f32_16x16x32_bf16(a, b, c, 0, 0, 0);
}
__device__ __forceinline__ unsigned bperm(int addr, unsigned v) {
    return (unsigned)__builtin_amdgcn_ds_bpermute(addr, (int)v);
}
// DPP helpers: quad_perm xor1 = 0xB1, xor2 = 0x4E; row_shl:N = 0x100+N (lane i <- lane i+N)
template<int CTRL>
__device__ __forceinline__ unsigned dppu(unsigned v) {
    return (unsigned)__builtin_amdgcn_update_dpp((int)v, (int)v, CTRL, 0xF, 0xF, false);
}
template<int CTRL>
__device__ __forceinline__ float dppf(float v) {
    int i = __builtin_bit_cast(int, v);
    return __builtin_bit_cast(float, __builtin_amdgcn_update_dpp(i, i, CTRL, 0xF, 0xF, false));
}
#define DPP_XOR1 0xB1
#define DPP_XOR2 0x4E
#define DPP_SHL1 0x101
#define DPP_SHL4 0x104
#define DPP_SHL5 0x105

// raw transcendental builtins: single v_exp_f32 / v_log_f32 (no OCML edge-handling)
__device__ __forceinline__ float ex2(float x) { return __builtin_amdgcn_exp2f(x); }
__device__ __forceinline__ float lg2(float x) { return __builtin_amdgcn_logf(x); }
// gates with log2e pre-folded into weights: no scale muls on the chain
__device__ __forceinline__ float sig2(float xs)  { return __builtin_amdgcn_rcpf(1.f + ex2(-xs)); }
__device__ __forceinline__ float tanh2(float ys) { return 1.f - 2.f * __builtin_amdgcn_rcpf(ex2(ys) + 1.f); }
__device__ __forceinline__ f32x4 ld4(const float* p) { return *(const f32x4*)p; }

__device__ __forceinline__ void packC(unsigned* P, f32x4 a0, f32x4 a1, bool oob) {
    float r0 = fmaxf(a0[0], 0.f), r1 = fmaxf(a0[1], 0.f), r2 = fmaxf(a0[2], 0.f), r3 = fmaxf(a0[3], 0.f);
    float s0 = fmaxf(a1[0], 0.f), s1 = fmaxf(a1[1], 0.f), s2 = fmaxf(a1[2], 0.f), s3 = fmaxf(a1[3], 0.f);
    P[0] = pack_trunc(r1, r0); P[1] = pack_trunc(r3, r2);
    P[2] = pack_trunc(s1, s0); P[3] = pack_trunc(s3, s2);
    if (oob) { P[0] = 0u; P[1] = 0u; P[2] = 0u; P[3] = 0u; }
}

// ===================== prep kernel: MLP compose + frag prepack =====================
__global__ __launch_bounds__(256) void r2p2_prep(
    const float* __restrict__ w0, const float* __restrict__ w1,
    const float* __restrict__ w2, const float* __restrict__ w3,
    const float* __restrict__ enc_whh,
    const float* __restrict__ dec_wih, const float* __restrict__ dec_whh,
    const float* __restrict__ mw1, const float* __restrict__ mb1,
    const float* __restrict__ mw2, const float* __restrict__ mb2,
    float* __restrict__ wsf, unsigned* __restrict__ wsu) {
    const int tid = threadIdx.x, bx = blockIdx.x;
    if (bx == 0) {
        // ---- composed MLP, coalesced: threads 0..127 -> M[j][k]; 128..191 -> c partials ----
        __shared__ float red[64];
        if (tid < 128) {
            int k = tid & 31, j = tid >> 5;
            const float* w2r = mw2 + j * 512;
            float a0 = 0.f, a1 = 0.f, a2 = 0.f, a3 = 0.f;
#pragma unroll 4
            for (int m = 0; m < 512; m += 4) {
                a0 = fmaf(w2r[m],     mw1[m * 32 + k],       a0);
                a1 = fmaf(w2r[m + 1], mw1[(m + 1) * 32 + k], a1);
                a2 = fmaf(w2r[m + 2], mw1[(m + 2) * 32 + k], a2);
                a3 = fmaf(w2r[m + 3], mw1[(m + 3) * 32 + k], a3);
            }
            wsf[j * 32 + k] = (a0 + a1) + (a2 + a3);
        } else if (tid < 192) {
            int t = tid - 128;          // 0..63: j = t&3, chunk = t>>2 (16 chunks of 32)
            int j = t & 3, ch = t >> 2;
            const float* w2c = mw2 + j * 512 + ch * 32;
            const float* b1c = mb1 + ch * 32;
            float p = 0.f;
#pragma unroll 8
            for (int m = 0; m < 32; ++m) p = fmaf(w2c[m], b1c[m], p);
            red[t] = p;
        }
        __syncthreads();
        if (tid < 4) {
            float c = mb2[tid];
#pragma unroll
            for (int i = 0; i < 16; ++i) c += red[tid + i * 4];
            wsf[128 + tid] = c;
        }
        return;
    }
    // ---- frag prepack: 44 frags x 64 lanes, cells split over blocks 1..7 ----
    // GRU frags (f>=26) pre-scaled: R/Z gates by log2e, N gate by 2*log2e (folds the
    // exp/tanh argument scaling out of the recurrent hot path).
    int base = (bx - 1) * 416;
    for (int c = base + tid; c < base + 416 && c < 2816; c += 256) {
        int f = c >> 6, lane = c & 63;
        int n = lane & 15, q = lane >> 4;
        int pc0 = ((n >> 2) << 3) | (n & 3);
        float v[8];
        float sc = 1.f;
        if (f < 2) {
            int co = pc0 + f * 4;
#pragma unroll
            for (int j = 0; j < 8; ++j) v[j] = (q == 0) ? w0[j * 32 + co] : 0.f;
        } else if (f < 26) {
            int t = f - 2;
            const float* W = (t < 8) ? w1 : (t < 16) ? w2 : w3;
            t &= 7;
            int mt = t >> 2, ks = t & 3, co = pc0 + mt * 4;
#pragma unroll
            for (int j = 0; j < 8; ++j) v[j] = W[(ks * 32 + q * 8 + j) * 32 + co];
        } else if (f < 32) {
            int t = f - 26, gate = t >> 1, mt = t & 1;
            sc = (gate == 2) ? L2E2 : L2E;
            int row = gate * 32 + pc0 + mt * 4;
#pragma unroll
            for (int j = 0; j < 8; ++j) v[j] = dec_wih[row * 34 + 2 + q * 8 + j];
        } else if (f < 38) {
            int t = f - 32, gate = t >> 1, mt = t & 1;
            sc = (gate == 2) ? L2E2 : L2E;
            int row = gate * 32 + pc0 + mt * 4;
#pragma unroll
            for (int j = 0; j < 8; ++j) v[j] = dec_whh[row * 32 + q * 8 + j];
        } else {
            int t = f - 38, gate = t >> 1, mt = t & 1;
            sc = (gate == 2) ? L2E2 : L2E;
            int row = gate * 32 + pc0 + mt * 4;
#pragma unroll
            for (int j = 0; j < 8; ++j) v[j] = enc_whh[row * 32 + q * 8 + j];
        }
#pragma unroll
        for (int j = 0; j < 8; ++j) v[j] *= sc;
        uint4v u;
        u[0] = packRNE(v[1], v[0]); u[1] = packRNE(v[3], v[2]);
        u[2] = packRNE(v[5], v[4]); u[3] = packRNE(v[7], v[6]);
        *(uint4v*)(wsu + FRAG0 + f * 256 + lane * 4) = u;
    }
}

// ===================== main kernel =====================
__global__ __launch_bounds__(256)
void r2p2_main(
    const float* __restrict__ z, const float* __restrict__ past, const float* __restrict__ lidar,
    const float* __restrict__ b0, const float* __restrict__ b1,
    const float* __restrict__ b2, const float* __restrict__ b3,
    const float* __restrict__ enc_wih, const float* __restrict__ enc_bih, const float* __restrict__ enc_bhh,
    const float* __restrict__ dec_wih, const float* __restrict__ dec_bih, const float* __restrict__ dec_bhh,
    const float* __restrict__ wsf, const unsigned* __restrict__ wsu,
    float* __restrict__ out) {

    const int tid = threadIdx.x, b = blockIdx.x;
    const int wid = tid >> 6, lane = tid & 63;
    const int n = lane & 15, q = lane >> 4, e = n & 1;

    __shared__ __align__(16) unsigned sLID[104 * 104];
    __shared__ __align__(16) float PASTs[40];
    __shared__ __align__(16) float ZVs[64];

    if (wid != 0) {
        // ====== waves 1-3: lidar staging + z (z pre-scaled by ln2 for softplus folding) ======
        int st = tid - 64;   // 0..191
        if (st < 60) ZVs[st] = z[b * 60 + st] * LN2;
        for (int i = st; i < 816; i += 192) {   // zero border
            int idx = (i < 416) ? (10400 + i) : ((((i - 416) >> 2) * 104) + 100 + ((i - 416) & 3));
            sLID[idx] = 0u;
        }
        const float4* lp4 = (const float4*)(lidar + (size_t)b * 20000);
#pragma unroll 4
        for (int i = st; i < 5000; i += 192) {
            int r = (int)(((unsigned)i * 5243u) >> 18);   // i / 50
            int c2 = i - r * 50;
            float4 v = lp4[i];
            int o = r * 104 + 2 * c2;
            sLID[o]     = pack_trunc(v.y, v.x);
            sLID[o + 1] = pack_trunc(v.w, v.z);
        }
        __syncthreads();
        return;
    }

    // ====== wave 0: coalesced frag loads ======
    uint4v FR[44];
#pragma unroll
    for (int f = 0; f < 44; ++f) FR[f] = *(const uint4v*)(wsu + FRAG0 + f * 256 + lane * 4);
#define FRG(f) __builtin_bit_cast(short8, FR[f])

    f32x4 cb0[2], cb1[2], cb2[2], cb3[2], gbR[2], gbZ[2], gbNi[2], gbNh[2];
    f32x4 egR[2], egZ[2], egNh[2];
#pragma unroll
    for (int mt = 0; mt < 2; ++mt) {
        int o = q * 8 + mt * 4;
        cb0[mt] = ld4(b0 + o); cb1[mt] = ld4(b1 + o); cb2[mt] = ld4(b2 + o); cb3[mt] = ld4(b3 + o);
        gbR[mt]  = (ld4(dec_bih + o)      + ld4(dec_bhh + o))      * L2E;
        gbZ[mt]  = (ld4(dec_bih + 32 + o) + ld4(dec_bhh + 32 + o)) * L2E;
        gbNi[mt] = ld4(dec_bih + 64 + o) * L2E2;
        gbNh[mt] = ld4(dec_bhh + 64 + o) * L2E2;
        egR[mt]  = (ld4(enc_bih + o)      + ld4(enc_bhh + o))      * L2E;
        egZ[mt]  = (ld4(enc_bih + 32 + o) + ld4(enc_bhh + 32 + o)) * L2E;
        egNh[mt] = ld4(enc_bhh + 64 + o) * L2E2;
    }
    f32x4 ebni = ld4(enc_bih + 64 + q * 8 + e * 4) * L2E2;
    float2 wxr[4], wxz[4], wxn[4], wexr[4], wexz[4], wexn[4];
#pragma unroll
    for (int r = 0; r < 4; ++r) {
        int c = q * 8 + e * 4 + r;
        wxr[r]  = *(const float2*)(dec_wih + c * 34);
        wxz[r]  = *(const float2*)(dec_wih + (32 + c) * 34);
        wxn[r]  = *(const float2*)(dec_wih + (64 + c) * 34);
        wexr[r] = *(const float2*)(enc_wih + c * 2);
        wexz[r] = *(const float2*)(enc_wih + (32 + c) * 2);
        wexn[r] = *(const float2*)(enc_wih + (64 + c) * 2);
        wxr[r].x *= L2E;  wxr[r].y *= L2E;   wxz[r].x *= L2E;  wxz[r].y *= L2E;
        wxn[r].x *= L2E2; wxn[r].y *= L2E2;
        wexr[r].x *= L2E; wexr[r].y *= L2E;  wexz[r].x *= L2E; wexz[r].y *= L2E;
        wexn[r].x *= L2E2; wexn[r].y *= L2E2;
    }
    // head rows 2,3 (scale outputs) pre-scaled by log2e -> softplus in base-2
    short8 Am = (short8)0;
    if (n < 4) {
        float sc = (n >= 2) ? L2E : 1.f;
#pragma unroll
        for (int j = 0; j < 8; ++j) Am[j] = (short)f2bf(wsf[n * 32 + q * 8 + j] * sc);
    }
    f32x4 mcv = {0.f, 0.f, 0.f, 0.f};
    if (q == 0) {
        mcv = *(const f32x4*)(wsf + 128);
        mcv[2] *= L2E; mcv[3] *= L2E;
    }

    if (lane < 20) *(float2*)&PASTs[2 * lane] = *(const float2*)(past + b * 40 + 2 * lane);
    float q0 = past[b * 40 + 38], q1 = past[b * 40 + 39];
    float p0 = past[b * 40 + 36], p1 = past[b * 40 + 37];
    asm volatile("s_waitcnt lgkmcnt(0)" ::: "memory");

    // ====== encoder: register GRU, 20 steps ======
    float hq[4] = {0.f, 0.f, 0.f, 0.f};
    short8 hfr = (short8)0;
#pragma unroll 1
    for (int t = 0; t < 20; ++t) {
        float2 xp = *(const float2*)&PASTs[2 * t];
        f32x4 gr0 = mfma16(FRG(38), hfr, egR[0]),  gr1 = mfma16(FRG(39), hfr, egR[1]);
        f32x4 gz0 = mfma16(FRG(40), hfr, egZ[0]),  gz1 = mfma16(FRG(41), hfr, egZ[1]);
        f32x4 gh0 = mfma16(FRG(42), hfr, egNh[0]), gh1 = mfma16(FRG(43), hfr, egNh[1]);
        f32x4 grS = e ? gr1 : gr0, gzS = e ? gz1 : gz0, ghS = e ? gh1 : gh0;
        float hn[4];
#pragma unroll
        for (int r = 0; r < 4; ++r) {
            float xr = fmaf(xp.y, wexr[r].y, xp.x * wexr[r].x);
            float xz = fmaf(xp.y, wexz[r].y, xp.x * wexz[r].x);
            float xn = fmaf(xp.y, wexn[r].y, xp.x * wexn[r].x);
            float rr = sig2(grS[r] + xr), zz = sig2(gzS[r] + xz);
            float tn = tanh2(fmaf(rr, ghS[r], ebni[r] + xn));
            float hv = tn + zz * (hq[r] - tn);
            hq[r] = hv; hn[r] = hv;
        }
        unsigned hu0 = cvtpk(hn[1], hn[0]), hu1 = cvtpk(hn[3], hn[2]);
        unsigned po0 = dppu<DPP_XOR1>(hu0), po1 = dppu<DPP_XOR1>(hu1);
        uint4v hv4;
        hv4[0] = e ? po0 : hu0; hv4[1] = e ? po1 : hu1;
        hv4[2] = e ? hu0 : po0; hv4[3] = e ? hu1 : po1;
        hfr = __builtin_bit_cast(short8, hv4);
    }

    // early-issue h-dependent decoder GRU MFMAs for step 0 (overlap sync wait)
    f32x4 hr0 = mfma16(FRG(32), hfr, gbR[0]);
    f32x4 hr1 = mfma16(FRG(33), hfr, gbR[1]);
    f32x4 hz0 = mfma16(FRG(34), hfr, gbZ[0]);
    f32x4 hz1 = mfma16(FRG(35), hfr, gbZ[1]);
    f32x4 hgn0 = mfma16(FRG(36), hfr, gbNh[0]);
    f32x4 hgn1 = mfma16(FRG(37), hfr, gbNh[1]);

    __syncthreads();   // join staging waves

    // ---- loop-invariant layout constants ----
    const int py1 = n >> 2, px1 = n & 3;       // conv1/conv2 column -> position (4-wide linear)
    const int woff = py1 * 104 + px1;          // per-lane sLID window base offset
    // conv3 gather (bpermute, replicated every quad) from conv2's 4-wide layout
    const int py3 = (n >> 1) & 1, px3 = n & 1;
    int adr3[4];
#pragma unroll
    for (int ks = 0; ks < 4; ++ks)
        adr3[ks] = (q * 16 + (py3 + (ks >> 1)) * 4 + px3 + (ks & 1)) * 4;
    const f32x4 zf4 = {0.f, 0.f, 0.f, 0.f};
    float la = 0.f;   // base-2 accumulator; converted at final store

    // ---- software-pipelined window state: loads issued at the tail of the previous
    //      iteration so the single-wave DS latency hides under tail + loop overhead ----
    float ay, ax; int limy, limx;
    unsigned W9[9];
    {
        float f0 = fminf(fmaxf(floorf(q0), 0.f), 98.f);
        float f1v = fminf(fmaxf(floorf(q1), 0.f), 98.f);
        int fy = (int)f0, fx = (int)f1v;
        ay = fminf(fmaxf(q0 - f0, 0.f), 1.f);
        ax = fminf(fmaxf(q1 - f1v, 0.f), 1.f);
        limy = 100 - fy; limx = 100 - fx;
        int bw = fy * 104 + fx + woff;
#pragma unroll
        for (int ry = 0; ry < 3; ++ry)
#pragma unroll
            for (int rx = 0; rx < 3; ++rx)
                W9[ry * 3 + rx] = sLID[bw + ry * 104 + rx];
    }

#pragma unroll 1
    for (int t = 0; t < 30; ++t) {
        float2 zv = *(const float2*)&ZVs[2 * t];

        // ---- fused conv0: 4 tap-aligned layouts, no conv1 gather (W9 preloaded) ----
        short8 bf1[4];
#pragma unroll
        for (int ks = 0; ks < 4; ++ks) {
            int dy = ks >> 1, dx = ks & 1;
            int wb = dy * 3 + dx;
            uint4v u;
            u[0] = W9[wb];     u[1] = W9[wb + 1];
            u[2] = W9[wb + 3]; u[3] = W9[wb + 4];
            short8 bq = __builtin_bit_cast(short8, u);
            f32x4 c0 = mfma16(FRG(0), bq, cb0[0]);
            f32x4 c1 = mfma16(FRG(1), bq, cb0[1]);
            unsigned P[4];
            packC(P, c0, c1, (py1 + dy >= limy) || (px1 + dx >= limx));
            uint4v up; up[0] = P[0]; up[1] = P[1]; up[2] = P[2]; up[3] = P[3];
            bf1[ks] = __builtin_bit_cast(short8, up);
        }

        // ---- conv1 ----
        unsigned Pa[4];
        {
            f32x4 aA = mfma16(FRG(2), bf1[0], cb1[0]); aA = mfma16(FRG(3), bf1[1], aA);
            f32x4 aB = mfma16(FRG(4), bf1[2], zf4);    aB = mfma16(FRG(5), bf1[3], aB);
            f32x4 bA = mfma16(FRG(6), bf1[0], cb1[1]); bA = mfma16(FRG(7), bf1[1], bA);
            f32x4 bB = mfma16(FRG(8), bf1[2], zf4);    bB = mfma16(FRG(9), bf1[3], bB);
            f32x4 o0 = aA + aB, o1 = bA + bB;
            packC(Pa, o0, o1, (py1 >= limy) || (px1 >= limx));
        }

        // ---- conv2 : DPP row_shl gather (sources lanes n+{0,1,4,5}) ----
        short8 bf2v[4];
        {
            uint4v g0, g1, g2, g3;
#pragma unroll
            for (int u = 0; u < 4; ++u) {
                g0[u] = Pa[u];
                g1[u] = dppu<DPP_SHL1>(Pa[u]);
                g2[u] = dppu<DPP_SHL4>(Pa[u]);
                g3[u] = dppu<DPP_SHL5>(Pa[u]);
            }
            bf2v[0] = __builtin_bit_cast(short8, g0);
            bf2v[1] = __builtin_bit_cast(short8, g1);
            bf2v[2] = __builtin_bit_cast(short8, g2);
            bf2v[3] = __builtin_bit_cast(short8, g3);
        }
        unsigned Pb[4];
        {
            f32x4 aA = mfma16(FRG(10), bf2v[0], cb2[0]); aA = mfma16(FRG(11), bf2v[1], aA);
            f32x4 aB = mfma16(FRG(12), bf2v[2], zf4);    aB = mfma16(FRG(13), bf2v[3], aB);
            f32x4 bA = mfma16(FRG(14), bf2v[0], cb2[1]); bA = mfma16(FRG(15), bf2v[1], bA);
            f32x4 bB = mfma16(FRG(16), bf2v[2], zf4);    bB = mfma16(FRG(17), bf2v[3], bB);
            f32x4 o0 = aA + aB, o1 = bA + bB;
            packC(Pb, o0, o1, (py1 >= limy) || (px1 >= limx));
        }

        // ---- conv3 (bpermute, quad-replicated) + bilinear (DPP quad butterfly) ----
        short8 bf3v[4];
#pragma unroll
        for (int ks = 0; ks < 4; ++ks) {
            uint4v bu;
#pragma unroll
            for (int u = 0; u < 4; ++u) bu[u] = bperm(adr3[ks], Pb[u]);
            bf3v[ks] = __builtin_bit_cast(short8, bu);
        }
        short8 xf;
        {
            f32x4 aA = mfma16(FRG(18), bf3v[0], cb3[0]); aA = mfma16(FRG(19), bf3v[1], aA);
            f32x4 aB = mfma16(FRG(20), bf3v[2], zf4);    aB = mfma16(FRG(21), bf3v[3], aB);
            f32x4 bA = mfma16(FRG(22), bf3v[0], cb3[1]); bA = mfma16(FRG(23), bf3v[1], bA);
            f32x4 bB = mfma16(FRG(24), bf3v[2], zf4);    bB = mfma16(FRG(25), bf3v[3], bB);
            f32x4 o0 = aA + aB, o1 = bA + bB;
            float wy = (n & 2) ? ay : 1.f - ay;
            float wx = (n & 1) ? ax : 1.f - ax;
            float w = wy * wx;
            float t0[4], t1[4];
#pragma unroll
            for (int r = 0; r < 4; ++r) { t0[r] = fmaxf(o0[r], 0.f) * w; t1[r] = fmaxf(o1[r], 0.f) * w; }
#pragma unroll
            for (int r = 0; r < 4; ++r) {
                t0[r] += dppf<DPP_XOR1>(t0[r]); t1[r] += dppf<DPP_XOR1>(t1[r]);
                t0[r] += dppf<DPP_XOR2>(t0[r]); t1[r] += dppf<DPP_XOR2>(t1[r]);
            }
            uint4v xu;
            xu[0] = cvtpk(t0[1], t0[0]); xu[1] = cvtpk(t0[3], t0[2]);
            xu[2] = cvtpk(t1[1], t1[0]); xu[3] = cvtpk(t1[3], t1[2]);
            xf = __builtin_bit_cast(short8, xu);
        }

        // ---- decoder GRU (h-dependent halves precomputed last step) ----
        f32x4 gr0 = mfma16(FRG(26), xf, hr0);
        f32x4 gr1 = mfma16(FRG(27), xf, hr1);
        f32x4 gz0 = mfma16(FRG(28), xf, hz0);
        f32x4 gz1 = mfma16(FRG(29), xf, hz1);
        f32x4 gi0 = mfma16(FRG(30), xf, gbNi[0]);
        f32x4 gi1 = mfma16(FRG(31), xf, gbNi[1]);
        // gate x-parts: computed here (under the MFMA latency above), short live range
        float xr[4], xz[4], xn[4];
#pragma unroll
        for (int r = 0; r < 4; ++r) {
            xr[r] = fmaf(q1, wxr[r].y, q0 * wxr[r].x);
            xz[r] = fmaf(q1, wxz[r].y, q0 * wxz[r].x);
            xn[r] = fmaf(q1, wxn[r].y, q0 * wxn[r].x);
        }
        f32x4 grS = e ? gr1 : gr0, gzS = e ? gz1 : gz0, giS = e ? gi1 : gi0, ghS = e ? hgn1 : hgn0;
        float hn[4];
#pragma unroll
        for (int r = 0; r < 4; ++r) {
            float rr = sig2(grS[r] + xr[r]), zz = sig2(gzS[r] + xz[r]);
            float tn = tanh2(fmaf(rr, ghS[r], giS[r] + xn[r]));
            float hv = tn + zz * (hq[r] - tn);
            hq[r] = hv; hn[r] = hv;
        }
        unsigned hu0 = cvtpk(hn[1], hn[0]), hu1 = cvtpk(hn[3], hn[2]);
        unsigned po0 = dppu<DPP_XOR1>(hu0), po1 = dppu<DPP_XOR1>(hu1);
        uint4v hv4;
        hv4[0] = e ? po0 : hu0; hv4[1] = e ? po1 : hu1;
        hv4[2] = e ? hu0 : po0; hv4[3] = e ? hu1 : po1;
        hfr = __builtin_bit_cast(short8, hv4);

        // ---- head ----
        f32x4 ls = mfma16(Am, hfr, mcv);

        // early-issue next step's h-dependent GRU MFMAs (overlap head/softplus/sLID)
        hr0 = mfma16(FRG(32), hfr, gbR[0]);
        hr1 = mfma16(FRG(33), hfr, gbR[1]);
        hz0 = mfma16(FRG(34), hfr, gbZ[0]);
        hz1 = mfma16(FRG(35), hfr, gbZ[1]);
        hgn0 = mfma16(FRG(36), hfr, gbNh[0]);
        hgn1 = mfma16(FRG(37), hfr, gbNh[1]);

        // ---- tail : base-2 softplus (raw v_exp/v_log), ln2 folded into zv and final la ----
        float l2 = ls[2], l3 = ls[3];    // pre-scaled by log2e via Am/mcv
        float s0 = fmaxf(l2, 0.f) + lg2(1.f + ex2(-fabsf(l2)));
        float s1 = fmaxf(l3, 0.f) + lg2(1.f + ex2(-fabsf(l3)));
        float ny0 = 2.f * q0 - p0 + ls[0] + s0 * zv.x;
        float ny1 = 2.f * q1 - p1 + ls[1] + s1 * zv.y;
        if (lane == 0) {
            float2 o2 = {ny0, ny1};
            *(float2*)(out + b * 60 + 2 * t) = o2;
        }
        p0 = q0; p1 = q1;
        q0 = rfl(ny0); q1 = rfl(ny1);

        // ---- issue next iteration's window loads ASAP (hide DS latency under la/store/loop) ----
        {
            float f0 = fminf(fmaxf(floorf(q0), 0.f), 98.f);
            float f1v = fminf(fmaxf(floorf(q1), 0.f), 98.f);
            int fy = (int)f0, fx = (int)f1v;
            ay = fminf(fmaxf(q0 - f0, 0.f), 1.f);
            ax = fminf(fmaxf(q1 - f1v, 0.f), 1.f);
            limy = 100 - fy; limx = 100 - fx;
            int bw = fy * 104 + fx + woff;
#pragma unroll
            for (int ry = 0; ry < 3; ++ry)
#pragma unroll
                for (int rx = 0; rx < 3; ++rx)
                    W9[ry * 3 + rx] = sLID[bw + ry * 104 + rx];
        }
        la += lg2(s0 * s1);
    }
    // la(base2) -> ln: la_e = ln2*la + 60*ln(ln2)   (s = ln2*sp per scale, 2 scales/step)
    if (lane == 0) out[15360 + b] = fmaf(LN2, la, -21.990775f);
#undef FRG
}

extern "C" void kernel_launch(void* const* d_in, const int* in_sizes, int n_in,
                              void* d_out, int out_size, void* d_ws, size_t ws_size,
                              hipStream_t stream) {
    const float* z    = (const float*)d_in[0];
    const float* past = (const float*)d_in[1];
    const float* lid  = (const float*)d_in[2];
    const float* c0w = (const float*)d_in[3];  const float* c0b = (const float*)d_in[4];
    const float* c1w = (const float*)d_in[5];  const float* c1b = (const float*)d_in[6];
    const float* c2w = (const float*)d_in[7];  const float* c2b = (const float*)d_in[8];
    const float* c3w = (const float*)d_in[9];  const float* c3b = (const float*)d_in[10];
    const float* ewih = (const float*)d_in[11]; const float* ewhh = (const float*)d_in[12];
    const float* ebih = (const float*)d_in[13]; const float* ebhh = (const float*)d_in[14];
    const float* dwih = (const float*)d_in[15]; const float* dwhh = (const float*)d_in[16];
    const float* dbih = (const float*)d_in[17]; const float* dbhh = (const float*)d_in[18];
    const float* mw1 = (const float*)d_in[19]; const float* mb1 = (const float*)d_in[20];
    const float* mw2 = (const float*)d_in[21]; const float* mb2 = (const float*)d_in[22];
    float* out = (float*)d_out;
    float* wsf = (float*)d_ws;
    unsigned* wsu = (unsigned*)d_ws;

    r2p2_prep<<<8, 256, 0, stream>>>(c0w, c1w, c2w, c3w, ewhh, dwih, dwhh,
                                     mw1, mb1, mw2, mb2, wsf, wsu);
    r2p2_main<<<256, 256, 0, stream>>>(z, past, lid, c0b, c1b, c2b, c3b,
                                       ewih, ebih, ebhh, dwih, dbih, dbhh,
                                       wsf, wsu, out);
}